// Round 10
// baseline (273.332 us; speedup 1.0000x reference)
//
#include <hip/hip_runtime.h>

#define N_NODES 50000
#define N_EDGES 1600000
#define ET (N_EDGES + N_NODES)   // edges + self-loops
#define DF 128                   // feature / hidden dim
#define SLOPE 0.2f

#define NB2 391       // fine buckets: dst >> 7 (50000/128)
#define CAP2 6144     // slots per bucket (avg ~4220, sigma ~65 -> +29 sigma)
#define P1_CHUNK 4096 // edges per bin block (16 per thread)
#define GEMM_BLOCKS ((N_NODES + 63) / 64)            // 782 (64-row tiles)
#define BIN_BLOCKS ((ET + P1_CHUNK - 1) / P1_CHUNK)  // 403
#define WCONV_BLOCKS 256
#define AGG_HALF 25000
#define AGG_HALF_BLOCKS (AGG_HALF / 4)               // 6250

typedef __attribute__((ext_vector_type(4))) float floatx4;     // MFMA C/D
typedef __attribute__((ext_vector_type(8))) _Float16 half8;    // 8 fp16 (16 B)
typedef __attribute__((ext_vector_type(2))) _Float16 half2v;   // fdot2 operand

// ---------------------------------------------------------------------------
// W prep body: casts the four 128x128 W matrices to fp16 (R20-validated:
// absmax unchanged), stored in the GEMM's LDS-image order [slab][quad][col][j]
// (slab=k>>5, quad=(k>>3)&3, j=k&7). Reads coalesced (c inner).
// ---------------------------------------------------------------------------
__device__ __forceinline__ void wconv_body(
    int bid,
    const float* __restrict__ W0, const float* __restrict__ W1,
    const float* __restrict__ W2, const float* __restrict__ W3,
    _Float16* __restrict__ Wh)
{
    int idx = bid * 256 + threadIdx.x;   // 0..65535
    int m = idx >> 14, rem = idx & 16383;
    const float* W = (m == 0) ? W0 : (m == 1) ? W1 : (m == 2) ? W2 : W3;
    int c = rem & 127, k = rem >> 7;     // consecutive tid -> consecutive c
    float v = W[k * 128 + c];
    int slab = k >> 5, q = (k >> 3) & 3, j = k & 7;
    size_t o = (size_t)m * 16384 + (size_t)((slab << 2) + q) * 1024 + (c << 3) + j;
    Wh[o] = (_Float16)v;
}

// ---------------------------------------------------------------------------
// Bin body: CSR pass 1 (coarse bucket sort), fine buckets dst>>7.
// ---------------------------------------------------------------------------
__device__ __forceinline__ void bin_body(
    int bid, const int* __restrict__ ei,
    int* __restrict__ g_count, int* __restrict__ bucket_mem, char* smem_)
{
    int* cnt  = (int*)smem_;
    int* base = cnt + NB2;
    int* cnt2 = base + NB2;
    const int tid = threadIdx.x;

    for (int i = tid; i < NB2; i += 256) { cnt[i] = 0; cnt2[i] = 0; }
    __syncthreads();

    const int e0 = bid * P1_CHUNK;
    int srcv[16], dstv[16];
#pragma unroll
    for (int i = 0; i < 16; i++) {
        int eid = e0 + i * 256 + tid;   // coalesced
        int s = 0, d = -1;
        if (eid < ET) {
            if (eid < N_EDGES) { s = ei[eid]; d = ei[N_EDGES + eid]; }
            else               { s = d = eid - N_EDGES; }
        }
        srcv[i] = s; dstv[i] = d;
        if (d >= 0) atomicAdd(&cnt[d >> 7], 1);
    }
    __syncthreads();
    for (int i = tid; i < NB2; i += 256)
        base[i] = (cnt[i] > 0) ? atomicAdd(&g_count[i], cnt[i]) : 0;
    __syncthreads();
#pragma unroll
    for (int i = 0; i < 16; i++) {
        int d = dstv[i];
        if (d >= 0) {
            int b = d >> 7;
            int r = atomicAdd(&cnt2[b], 1);
            int slot = base[b] + r;
            if (slot < CAP2)
                bucket_mem[(size_t)b * CAP2 + slot] =
                    (srcv[i] & 0xFFFF) | ((d & 127) << 16);
        }
    }
}

// Dispatch 1: wconv (independent of edges) overlapped with bin pass.
__global__ __launch_bounds__(256) void prep_bin(
    const float* __restrict__ W0, const float* __restrict__ W1,
    const float* __restrict__ W2, const float* __restrict__ W3,
    _Float16* __restrict__ Wh,
    const int* __restrict__ ei,
    int* __restrict__ g_count, int* __restrict__ bucket_mem)
{
    __shared__ char smem[4704];   // 3 * 391 ints
    if (blockIdx.x < WCONV_BLOCKS)
        wconv_body(blockIdx.x, W0, W1, W2, W3, Wh);
    else
        bin_body(blockIdx.x - WCONV_BLOCKS, ei, g_count, bucket_mem, smem);
}

__device__ __forceinline__ half8 load_h8(const float* p) {
    float4 a = *(const float4*)(p);
    float4 b = *(const float4*)(p + 4);
    half8 h;
    h[0] = (_Float16)a.x; h[1] = (_Float16)a.y;
    h[2] = (_Float16)a.z; h[3] = (_Float16)a.w;
    h[4] = (_Float16)b.x; h[5] = (_Float16)b.y;
    h[6] = (_Float16)b.z; h[7] = (_Float16)b.w;
    return h;
}
__device__ __forceinline__ half8 load_h8(const _Float16* p) {
    return *(const half8*)p;
}

// ---------------------------------------------------------------------------
// GEMM body: 256 threads (4 waves), 64-row tile, BK=32, single-fp16 W.
// W staged via global_load_lds. LDS 21,504 B.
// ---------------------------------------------------------------------------
template<typename T>
__device__ __forceinline__ void gemm_body(
    int bid, const T* __restrict__ X,
    const _Float16* __restrict__ WhL, const _Float16* __restrict__ WhR,
    _Float16* __restrict__ outL, _Float16* __restrict__ outR, int M, char* smem_)
{
    _Float16* xs  = (_Float16*)smem_;      // 64*40 halves (5,120 B)
    _Float16* whL = xs + 64 * 40;          // 4096 halves (8,192 B)
    _Float16* whR = whL + 4096;            // total 21,504 B

    const int t = threadIdx.x;             // 0..255
    const int row0 = bid * 64;
    const int lane = t & 63, wv = t >> 6;  // 4 waves
    const int lm = lane & 15, quad = lane >> 4;
    const int m0 = wv * 16;

    floatx4 accL[8], accR[8];
#pragma unroll
    for (int i = 0; i < 8; i++) { accL[i] = (floatx4)0.f; accR[i] = (floatx4)0.f; }

    const int sr = t >> 2;          // X stage: row 0..63 (4 thr/row)
    const int sc = (t & 3) * 8;     // X stage: k offset

    for (int kb = 0; kb < 128; kb += 32) {
        const int slab = kb >> 5;
        int xrow = row0 + sr; if (xrow >= M) xrow = M - 1;
        half8 xv = load_h8(X + (size_t)xrow * DF + kb + sc);
        *(half8*)&xs[sr * 40 + sc] = xv;

        // W stage: direct global->LDS DMA. Chunk = 64 lanes x 16 B = 1 KB;
        // 8 chunks per 8 KB buffer; wave wv stages chunks wv*2, wv*2+1.
        {
#pragma unroll
            for (int i = 0; i < 2; i++) {
                const int chunk = wv * 2 + i;
                const size_t sbase = (size_t)slab * 4096 + chunk * 512 + lane * 8;
                __builtin_amdgcn_global_load_lds(
                    (const __attribute__((address_space(1))) void*)(WhL + sbase),
                    (__attribute__((address_space(3))) void*)(whL + chunk * 512),
                    16, 0, 0);
                __builtin_amdgcn_global_load_lds(
                    (const __attribute__((address_space(1))) void*)(WhR + sbase),
                    (__attribute__((address_space(3))) void*)(whR + chunk * 512),
                    16, 0, 0);
            }
        }
        __syncthreads();

        half8 af = *(const half8*)&xs[(m0 + lm) * 40 + quad * 8];
#pragma unroll
        for (int nt = 0; nt < 8; nt++) {
            const int bofs = quad * 1024 + (nt * 16 + lm) * 8;
            half8 bh = *(const half8*)&whL[bofs];
            accL[nt] = __builtin_amdgcn_mfma_f32_16x16x32_f16(af, bh, accL[nt], 0, 0, 0);
            half8 ch = *(const half8*)&whR[bofs];
            accR[nt] = __builtin_amdgcn_mfma_f32_16x16x32_f16(af, ch, accR[nt], 0, 0, 0);
        }
        __syncthreads();
    }

#pragma unroll
    for (int nt = 0; nt < 8; nt++) {
        int col = (nt >> 2) * 64 + (nt & 3) * 16 + lm;
#pragma unroll
        for (int r = 0; r < 4; r++) {
            int gr = row0 + m0 + quad * 4 + r;
            if (gr < M) {
                size_t o = (size_t)gr * DF + col;
                outL[o] = (_Float16)accL[nt][r];
                outR[o] = (_Float16)accR[nt][r];
            }
        }
    }
}

// ---------------------------------------------------------------------------
// CSR pass 2 body: one 256-thread block per fine bucket (391 blocks).
// ---------------------------------------------------------------------------
__device__ __forceinline__ void csr_body(
    int b, const int* __restrict__ g_count, const int* __restrict__ bucket_mem,
    int* __restrict__ row_ptr, unsigned short* __restrict__ csr_src, char* smem_)
{
    int* sh_edges = (int*)smem_;          // 6144 ints
    int* hist = sh_edges + 6144;          // 128
    int* excl = hist + 128;               // 128
    int* cnt2 = excl + 128;               // 128
    int* sA   = cnt2 + 128;               // 512
    int* sB   = sA + 512;                 // 512
    const int tid = threadIdx.x;          // 0..255

    // inclusive prefix scan over 391 bucket sizes (padded to 512)
    sA[tid]       = (tid < NB2)       ? g_count[tid]       : 0;
    sA[tid + 256] = (tid + 256 < NB2) ? g_count[tid + 256] : 0;
    __syncthreads();
    int* in = sA; int* outp = sB;
    for (int d = 1; d < 512; d <<= 1) {
        for (int i = tid; i < 512; i += 256)
            outp[i] = in[i] + ((i >= d) ? in[i - d] : 0);
        __syncthreads();
        int* tmp = in; in = outp; outp = tmp;
    }
    const int base_csr = (b > 0) ? in[b - 1] : 0;

    int m = g_count[b]; if (m > CAP2) m = CAP2;
    if (tid < 128) { hist[tid] = 0; cnt2[tid] = 0; }
    __syncthreads();
    const int* bm = bucket_mem + (size_t)b * CAP2;
    for (int i = tid; i < m; i += 256) {
        int p = bm[i];
        sh_edges[i] = p;
        atomicAdd(&hist[(p >> 16) & 127], 1);
    }
    __syncthreads();
    if (tid < 128) sA[tid] = hist[tid];
    __syncthreads();
    for (int d = 1; d < 128; d <<= 1) {
        int x = 0;
        if (tid < 128 && tid >= d) x = sA[tid - d];
        __syncthreads();
        if (tid < 128) sA[tid] += x;
        __syncthreads();
    }
    if (tid < 128) {
        excl[tid] = sA[tid] - hist[tid];
        int node = (b << 7) + tid;
        if (node < N_NODES) row_ptr[node] = base_csr + excl[tid];
    }
    if (b == 0 && tid == 0) row_ptr[N_NODES] = ET;
    __syncthreads();
    for (int i = tid; i < m; i += 256) {
        int p = sh_edges[i];
        int dl = (p >> 16) & 127;
        int r = atomicAdd(&cnt2[dl], 1);
        csr_src[base_csr + excl[dl] + r] = (unsigned short)(p & 0xFFFF);
    }
}

// Dispatch 2: layer-1 GEMM overlapped with CSR pass 2.
__global__ __launch_bounds__(256) void gemm_csr(
    const float* __restrict__ X,
    const _Float16* __restrict__ WhL, const _Float16* __restrict__ WhR,
    _Float16* __restrict__ outL, _Float16* __restrict__ outR,
    const int* __restrict__ g_count, const int* __restrict__ bucket_mem,
    int* __restrict__ row_ptr, unsigned short* __restrict__ csr_src)
{
    __shared__ char smem[30720];
    if (blockIdx.x < GEMM_BLOCKS)
        gemm_body<float>(blockIdx.x, X, WhL, WhR, outL, outR, N_NODES, smem);
    else
        csr_body(blockIdx.x - GEMM_BLOCKS, g_count, bucket_mem,
                 row_ptr, csr_src, smem);
}

// Layer-2 GEMM: fp16 input (layer-1 activations; zero-cvt staging).
__global__ __launch_bounds__(256) void gemm_f16(
    const _Float16* __restrict__ X,
    const _Float16* __restrict__ WhL, const _Float16* __restrict__ WhR,
    _Float16* __restrict__ outL, _Float16* __restrict__ outR)
{
    __shared__ char smem[21504];
    gemm_body<_Float16>(blockIdx.x, X, WhL, WhR, outL, outR, N_NODES, smem);
}

// ---------------------------------------------------------------------------
// Full-width fused scores + softmax + aggregate.
// R22: (a) split into two half-range dispatches (node0 = 0 / 25000) --
// instrumentation: halves agg dispatch duration to ~28 us so the rocprof
// top-5 surfaces the slowest NON-agg kernel, which has been invisible for
// 4 rounds; (b) att pre-scaled by log2(e) at setup so per-edge exp is a
// bare v_exp (exp2f) instead of v_mul+v_exp. Numerics shift <= 1 ulp in e.
// ---------------------------------------------------------------------------
template<typename TOut>
__global__ __launch_bounds__(256) void fused_agg(
    const _Float16* __restrict__ XL, const _Float16* __restrict__ XR,
    const int* __restrict__ row_ptr, const unsigned short* __restrict__ csr_src,
    const float* __restrict__ att, const float* __restrict__ bias,
    TOut* __restrict__ out, int node0)
{
    const int t = threadIdx.x;
    const int wave = t >> 6, l = t & 63;
    const int g = l >> 4, gl = l & 15;       // edge group 0..3, lane in group
    const int n = node0 + blockIdx.x * 4 + wave;
    if (n >= N_NODES) return;
    const int beg = row_ptr[n], end = row_ptr[n + 1];
    const int deg = end - beg;
    const int dlim = (deg < 128) ? deg : 128;

    // ---- coalesced CSR-index preload: lane l holds positions l and l+64,
    // packed low/high 16 bits (node ids < 50000 fit in 16 bits).
    const int liA = beg + l, liB = liA + 64;
    unsigned sa = (liA < end) ? (unsigned)csr_src[liA] : 0u;
    unsigned sb = (liB < end) ? (unsigned)csr_src[liB] : 0u;
    const unsigned s32 = sa | (sb << 16);

    const int c0 = gl * 8;                   // channels c0..c0+7
    half8 xrh = *(const half8*)(XR + (size_t)n * DF + c0);
    // att pre-scaled by log2(e): score accumulates in log2 domain, exp via
    // bare v_exp_f32 (exp2f). <=1 ulp difference vs __expf.
    const float LOG2E = 1.44269504088896340736f;
    float4 at0 = *(const float4*)(att + c0);
    float4 at1 = *(const float4*)(att + c0 + 4);
    half2v a01 = { (_Float16)(at0.x * LOG2E), (_Float16)(at0.y * LOG2E) };
    half2v a23 = { (_Float16)(at0.z * LOG2E), (_Float16)(at0.w * LOG2E) };
    half2v a45 = { (_Float16)(at1.x * LOG2E), (_Float16)(at1.y * LOG2E) };
    half2v a67 = { (_Float16)(at1.z * LOG2E), (_Float16)(at1.w * LOG2E) };
    const half8 slp = { (_Float16)SLOPE, (_Float16)SLOPE, (_Float16)SLOPE, (_Float16)SLOPE,
                        (_Float16)SLOPE, (_Float16)SLOPE, (_Float16)SLOPE, (_Float16)SLOPE };

    float a0 = 0.f, a1 = 0.f, a2 = 0.f, a3 = 0.f;
    float a4 = 0.f, a5 = 0.f, a6 = 0.f, a7 = 0.f, den = 0.f;

    // source index for edge position POS (0..127): one ds_bpermute + select.
#define SRC(POS)                                                               \
    ({ int _p = (POS);                                                         \
       unsigned _v = (unsigned)__shfl((int)s32, _p & 63);                      \
       (int)(((_p & 64) ? (_v >> 16) : _v) & 0xFFFFu); })
#define LDROW(S) (*(const half8*)(XL + ((size_t)(unsigned)(S) << 7) + c0))

    // NOTE: _ok MUST be evaluated before any macro-local declarations so the
    // EOK expression sees the enclosing scope's loop variable (macro hygiene).
    // Score: FOUR fdot2 chains (m01,m23,m45,m67) -- all 8 channels.
#define EDGE_STEP(HV, EOK)                                                     \
    {                                                                          \
        const bool _ok = (EOK);                                                \
        half8 _msg = HV + xrh;                                                 \
        half8 _lk  = __builtin_elementwise_max(_msg, _msg * slp);              \
        half2v _m01 = { _lk[0], _lk[1] };                                      \
        half2v _m23 = { _lk[2], _lk[3] };                                      \
        half2v _m45 = { _lk[4], _lk[5] };                                      \
        half2v _m67 = { _lk[6], _lk[7] };                                      \
        float _sc = __builtin_amdgcn_fdot2(_m01, a01, 0.f, false);             \
        _sc = __builtin_amdgcn_fdot2(_m23, a23, _sc, false);                   \
        _sc = __builtin_amdgcn_fdot2(_m45, a45, _sc, false);                   \
        _sc = __builtin_amdgcn_fdot2(_m67, a67, _sc, false);                   \
        _sc += __shfl_xor(_sc, 1);                                             \
        _sc += __shfl_xor(_sc, 2);                                             \
        float _e = _ok ? exp2f(_sc) : 0.f;                                     \
        uint4 _hw; __builtin_memcpy(&_hw, &(HV), 16);                          \
        asm("v_fma_mix_f32 %0, %1, %2, %0 op_sel:[0,0,0] op_sel_hi:[1,0,0]"    \
            : "+v"(a0) : "v"(_hw.x), "v"(_e));                                 \
        asm("v_fma_mix_f32 %0, %1, %2, %0 op_sel:[1,0,0] op_sel_hi:[1,0,0]"    \
            : "+v"(a1) : "v"(_hw.x), "v"(_e));                                 \
        asm("v_fma_mix_f32 %0, %1, %2, %0 op_sel:[0,0,0] op_sel_hi:[1,0,0]"    \
            : "+v"(a2) : "v"(_hw.y), "v"(_e));                                 \
        asm("v_fma_mix_f32 %0, %1, %2, %0 op_sel:[1,0,0] op_sel_hi:[1,0,0]"    \
            : "+v"(a3) : "v"(_hw.y), "v"(_e));                                 \
        asm("v_fma_mix_f32 %0, %1, %2, %0 op_sel:[0,0,0] op_sel_hi:[1,0,0]"    \
            : "+v"(a4) : "v"(_hw.z), "v"(_e));                                 \
        asm("v_fma_mix_f32 %0, %1, %2, %0 op_sel:[1,0,0] op_sel_hi:[1,0,0]"    \
            : "+v"(a5) : "v"(_hw.z), "v"(_e));                                 \
        asm("v_fma_mix_f32 %0, %1, %2, %0 op_sel:[0,0,0] op_sel_hi:[1,0,0]"    \
            : "+v"(a6) : "v"(_hw.w), "v"(_e));                                 \
        asm("v_fma_mix_f32 %0, %1, %2, %0 op_sel:[1,0,0] op_sel_hi:[1,0,0]"    \
            : "+v"(a7) : "v"(_hw.w), "v"(_e));                                 \
        den += _e;                                                             \
    }

    // ---- ping-pong pipeline: 4 bufs = 16 positions in flight, phases of
    // 8 positions, zero register rotation.
    half8 X0 = LDROW(SRC(g));
    half8 X1 = LDROW(SRC(4 + g));
    half8 Y0 = LDROW(SRC(8 + g));
    half8 Y1 = LDROW(SRC(12 + g));

    int p = 0;
    for (;;) {
        // phase A: consume X0,X1 (pos p, p+4); refill with p+16, p+20
        EDGE_STEP(X0, (p + g < dlim))
        EDGE_STEP(X1, (p + 4 + g < dlim))
        X0 = LDROW(SRC(p + 16 + g));
        X1 = LDROW(SRC(p + 20 + g));
        p += 8;
        if (p >= dlim) break;
        // phase B: roles swapped
        EDGE_STEP(Y0, (p + g < dlim))
        EDGE_STEP(Y1, (p + 4 + g < dlim))
        Y0 = LDROW(SRC(p + 16 + g));
        Y1 = LDROW(SRC(p + 20 + g));
        p += 8;
        if (p >= dlim) break;
    }

    // ---- tail for deg > 128 (direct loads; never taken for this input) ----
    for (int q = 128; q < deg; q += 4) {
        int ei_ = beg + q + g;
        int s = (ei_ < end) ? (int)csr_src[ei_] : 0;
        half8 hvt = LDROW(s);
        EDGE_STEP(hvt, (q + g < deg))
    }
#undef EDGE_STEP
#undef SRC
#undef LDROW

#define CMB(x) x += __shfl_xor(x, 16); x += __shfl_xor(x, 32);
    CMB(a0) CMB(a1) CMB(a2) CMB(a3) CMB(a4) CMB(a5) CMB(a6) CMB(a7) CMB(den)
#undef CMB

    if (g == 0) {
        float inv = 1.f / (den + 1e-16f);     // den is this lane's head's total
        float4 b0 = *(const float4*)(bias + c0);
        float4 b1 = *(const float4*)(bias + c0 + 4);
        float o[8];
        o[0] = fmaxf(a0 * inv + b0.x, 0.f);
        o[1] = fmaxf(a1 * inv + b0.y, 0.f);
        o[2] = fmaxf(a2 * inv + b0.z, 0.f);
        o[3] = fmaxf(a3 * inv + b0.w, 0.f);
        o[4] = fmaxf(a4 * inv + b1.x, 0.f);
        o[5] = fmaxf(a5 * inv + b1.y, 0.f);
        o[6] = fmaxf(a6 * inv + b1.z, 0.f);
        o[7] = fmaxf(a7 * inv + b1.w, 0.f);
        TOut* op = out + (size_t)n * DF + c0;
        if constexpr (sizeof(TOut) == 2) {
            half8 hv;
#pragma unroll
            for (int i = 0; i < 8; i++) hv[i] = (_Float16)o[i];
            *(half8*)op = hv;
        } else {
            *(float4*)(op)     = make_float4(o[0], o[1], o[2], o[3]);
            *(float4*)(op + 4) = make_float4(o[4], o[5], o[6], o[7]);
        }
    }
}

// ---------------------------------------------------------------------------
extern "C" void kernel_launch(void* const* d_in, const int* in_sizes, int n_in,
                              void* d_out, int out_size, void* d_ws, size_t ws_size,
                              hipStream_t stream)
{
    (void)in_sizes; (void)n_in; (void)out_size; (void)ws_size;

    const float* x    = (const float*)d_in[0];
    const int*   ei   = (const int*)d_in[1];
    const float* W1l  = (const float*)d_in[2];
    const float* W1r  = (const float*)d_in[3];
    const float* att1 = (const float*)d_in[4];
    const float* b1   = (const float*)d_in[5];
    const float* W2l  = (const float*)d_in[6];
    const float* W2r  = (const float*)d_in[7];
    const float* att2 = (const float*)d_in[8];
    const float* b2   = (const float*)d_in[9];
    float* out = (float*)d_out;

    char* ws = (char*)d_ws;
    size_t off = 0;
    const size_t NF = (size_t)N_NODES * DF * sizeof(float);        // 25.6 MB
    _Float16* A = (_Float16*)(ws + off); off += NF / 2;            // xl fp16 [N][128]
    _Float16* B = (_Float16*)(ws + off); off += NF / 2;            // xr fp16 [N][128]
    _Float16* C = (_Float16*)(ws + off); off += NF / 2;            // layer-1 out fp16
    int* bucket_mem  = (int*)(ws + off); off += (size_t)NB2 * CAP2 * sizeof(int);
    int* g_count     = (int*)(ws + off); off += 512 * sizeof(int);
    int* row_ptr     = (int*)(ws + off); off += (size_t)(N_NODES + 1) * sizeof(int);
    unsigned short* csr_src = (unsigned short*)(ws + off);
    off += ((size_t)ET * sizeof(unsigned short) + 255) & ~(size_t)255;
    _Float16* Wh = (_Float16*)(ws + off); off += 4 * 16384 * sizeof(_Float16);

    // zero bucket counters (graph-capture-safe stream memset)
    hipMemsetAsync(g_count, 0, 512 * sizeof(int), stream);

    // ---- dispatch 1: W cast overlapped with CSR bin pass ----
    prep_bin<<<WCONV_BLOCKS + BIN_BLOCKS, 256, 0, stream>>>(
        W1l, W1r, W2l, W2r, Wh, ei, g_count, bucket_mem);

    // ---- dispatch 2: layer-1 GEMM overlapped with CSR pass 2 ----
    gemm_csr<<<GEMM_BLOCKS + NB2, 256, 0, stream>>>(
        x, Wh, Wh + 16384, A, B, g_count, bucket_mem, row_ptr, csr_src);

    // ---- layer-1 aggregation (two half-range dispatches) ----
    fused_agg<_Float16><<<AGG_HALF_BLOCKS, 256, 0, stream>>>(
        A, B, row_ptr, csr_src, att1, b1, C, 0);
    fused_agg<_Float16><<<AGG_HALF_BLOCKS, 256, 0, stream>>>(
        A, B, row_ptr, csr_src, att1, b1, C, AGG_HALF);

    // ---- layer 2 ----
    gemm_f16<<<GEMM_BLOCKS, 256, 0, stream>>>(
        C, Wh + 2 * 16384, Wh + 3 * 16384, A, B);
    fused_agg<float><<<AGG_HALF_BLOCKS, 256, 0, stream>>>(
        A, B, row_ptr, csr_src, att2, b2, out, 0);
    fused_agg<float><<<AGG_HALF_BLOCKS, 256, 0, stream>>>(
        A, B, row_ptr, csr_src, att2, b2, out, AGG_HALF);
}

// Round 12
// 255.078 us; speedup vs baseline: 1.0716x; 1.0716x over previous
//
#include <hip/hip_runtime.h>

#define N_NODES 50000
#define N_EDGES 1600000
#define ET (N_EDGES + N_NODES)   // edges + self-loops
#define DF 128                   // feature / hidden dim
#define SLOPE 0.2f

#define NB2 391       // fine buckets: dst >> 7 (50000/128)
#define CAP2 6144     // slots per bucket (avg ~4220, sigma ~65 -> +29 sigma)
#define P1_CHUNK 4096 // edges per bin block (16 per thread)
#define GEMM_BLOCKS2 ((N_NODES + 127) / 128)         // 391 (128-row tiles)
#define BIN_BLOCKS ((ET + P1_CHUNK - 1) / P1_CHUNK)  // 403
#define WCONV_BLOCKS 256

typedef __attribute__((ext_vector_type(4))) float floatx4;     // MFMA C/D
typedef __attribute__((ext_vector_type(8))) _Float16 half8;    // 8 fp16 (16 B)
typedef __attribute__((ext_vector_type(2))) _Float16 half2v;   // fdot2 operand

// ---------------------------------------------------------------------------
// W prep body: casts the four 128x128 W matrices to fp16 (R20-validated:
// absmax unchanged), stored in the GEMM's LDS-image order [slab][quad][col][j]
// (slab=k>>5, quad=(k>>3)&3, j=k&7). Reads coalesced (c inner, R21-validated).
// ---------------------------------------------------------------------------
__device__ __forceinline__ void wconv_body(
    int bid,
    const float* __restrict__ W0, const float* __restrict__ W1,
    const float* __restrict__ W2, const float* __restrict__ W3,
    _Float16* __restrict__ Wh)
{
    int idx = bid * 256 + threadIdx.x;   // 0..65535
    int m = idx >> 14, rem = idx & 16383;
    const float* W = (m == 0) ? W0 : (m == 1) ? W1 : (m == 2) ? W2 : W3;
    int c = rem & 127, k = rem >> 7;     // consecutive tid -> consecutive c
    float v = W[k * 128 + c];
    int slab = k >> 5, q = (k >> 3) & 3, j = k & 7;
    size_t o = (size_t)m * 16384 + (size_t)((slab << 2) + q) * 1024 + (c << 3) + j;
    Wh[o] = (_Float16)v;
}

// ---------------------------------------------------------------------------
// Bin body: CSR pass 1 (coarse bucket sort), fine buckets dst>>7.
// ---------------------------------------------------------------------------
__device__ __forceinline__ void bin_body(
    int bid, const int* __restrict__ ei,
    int* __restrict__ g_count, int* __restrict__ bucket_mem, char* smem_)
{
    int* cnt  = (int*)smem_;
    int* base = cnt + NB2;
    int* cnt2 = base + NB2;
    const int tid = threadIdx.x;

    for (int i = tid; i < NB2; i += 256) { cnt[i] = 0; cnt2[i] = 0; }
    __syncthreads();

    const int e0 = bid * P1_CHUNK;
    int srcv[16], dstv[16];
#pragma unroll
    for (int i = 0; i < 16; i++) {
        int eid = e0 + i * 256 + tid;   // coalesced
        int s = 0, d = -1;
        if (eid < ET) {
            if (eid < N_EDGES) { s = ei[eid]; d = ei[N_EDGES + eid]; }
            else               { s = d = eid - N_EDGES; }
        }
        srcv[i] = s; dstv[i] = d;
        if (d >= 0) atomicAdd(&cnt[d >> 7], 1);
    }
    __syncthreads();
    for (int i = tid; i < NB2; i += 256)
        base[i] = (cnt[i] > 0) ? atomicAdd(&g_count[i], cnt[i]) : 0;
    __syncthreads();
#pragma unroll
    for (int i = 0; i < 16; i++) {
        int d = dstv[i];
        if (d >= 0) {
            int b = d >> 7;
            int r = atomicAdd(&cnt2[b], 1);
            int slot = base[b] + r;
            if (slot < CAP2)
                bucket_mem[(size_t)b * CAP2 + slot] =
                    (srcv[i] & 0xFFFF) | ((d & 127) << 16);
        }
    }
}

// Dispatch 1: wconv (independent of edges) overlapped with bin pass.
__global__ __launch_bounds__(256) void prep_bin(
    const float* __restrict__ W0, const float* __restrict__ W1,
    const float* __restrict__ W2, const float* __restrict__ W3,
    _Float16* __restrict__ Wh,
    const int* __restrict__ ei,
    int* __restrict__ g_count, int* __restrict__ bucket_mem)
{
    __shared__ char smem[4704];   // 3 * 391 ints
    if (blockIdx.x < WCONV_BLOCKS)
        wconv_body(blockIdx.x, W0, W1, W2, W3, Wh);
    else
        bin_body(blockIdx.x - WCONV_BLOCKS, ei, g_count, bucket_mem, smem);
}

__device__ __forceinline__ half8 load_h8(const float* p) {
    float4 a = *(const float4*)(p);
    float4 b = *(const float4*)(p + 4);
    half8 h;
    h[0] = (_Float16)a.x; h[1] = (_Float16)a.y;
    h[2] = (_Float16)a.z; h[3] = (_Float16)a.w;
    h[4] = (_Float16)b.x; h[5] = (_Float16)b.y;
    h[6] = (_Float16)b.z; h[7] = (_Float16)b.w;
    return h;
}
__device__ __forceinline__ half8 load_h8(const _Float16* p) {
    return *(const half8*)p;
}

// ---------------------------------------------------------------------------
// GEMM body (R20 structure -- best measured, 256.4 us total): 512 threads
// (8 waves), 128-row tile, BK=32, single-fp16 W. Per K-step per wave:
// 16 MFMA, 2 global_load_lds chunks. LDS: xs 128x40 (10,240 B) + 2 x 8,192 B
// W buffers = 26,624 B.
// ---------------------------------------------------------------------------
template<typename T>
__device__ __forceinline__ void gemm_body(
    int bid, const T* __restrict__ X,
    const _Float16* __restrict__ WhL, const _Float16* __restrict__ WhR,
    _Float16* __restrict__ outL, _Float16* __restrict__ outR, int M, char* smem_)
{
    _Float16* xs  = (_Float16*)smem_;      // 128*40 halves (10,240 B)
    _Float16* whL = xs + 128 * 40;         // 4096 halves (8,192 B)
    _Float16* whR = whL + 4096;            // total 26,624 B

    const int t = threadIdx.x;             // 0..511
    const int row0 = bid * 128;
    const int lane = t & 63, wv = t >> 6;  // 8 waves
    const int lm = lane & 15, quad = lane >> 4;
    const int m0 = wv * 16;

    floatx4 accL[8], accR[8];
#pragma unroll
    for (int i = 0; i < 8; i++) { accL[i] = (floatx4)0.f; accR[i] = (floatx4)0.f; }

    const int sr = t >> 2;          // X stage: row 0..127 (4 thr/row)
    const int sc = (t & 3) * 8;     // X stage: k offset

    for (int kb = 0; kb < 128; kb += 32) {
        const int slab = kb >> 5;
        int xrow = row0 + sr; if (xrow >= M) xrow = M - 1;
        half8 xv = load_h8(X + (size_t)xrow * DF + kb + sc);
        *(half8*)&xs[sr * 40 + sc] = xv;

        // W stage: direct global->LDS DMA. Chunk = 64 lanes x 16 B = 1 KB
        // (512 halves); 8 chunks per 8 KB buffer; wave wv stages chunk wv
        // of each of the two buffers.
        {
            const size_t sbase = (size_t)slab * 4096 + wv * 512 + lane * 8;
            __builtin_amdgcn_global_load_lds(
                (const __attribute__((address_space(1))) void*)(WhL + sbase),
                (__attribute__((address_space(3))) void*)(whL + wv * 512),
                16, 0, 0);
            __builtin_amdgcn_global_load_lds(
                (const __attribute__((address_space(1))) void*)(WhR + sbase),
                (__attribute__((address_space(3))) void*)(whR + wv * 512),
                16, 0, 0);
        }
        __syncthreads();

        half8 af = *(const half8*)&xs[(m0 + lm) * 40 + quad * 8];
#pragma unroll
        for (int nt = 0; nt < 8; nt++) {
            const int bofs = quad * 1024 + (nt * 16 + lm) * 8;
            half8 bh = *(const half8*)&whL[bofs];
            accL[nt] = __builtin_amdgcn_mfma_f32_16x16x32_f16(af, bh, accL[nt], 0, 0, 0);
            half8 ch = *(const half8*)&whR[bofs];
            accR[nt] = __builtin_amdgcn_mfma_f32_16x16x32_f16(af, ch, accR[nt], 0, 0, 0);
        }
        __syncthreads();
    }

#pragma unroll
    for (int nt = 0; nt < 8; nt++) {
        int col = (nt >> 2) * 64 + (nt & 3) * 16 + lm;
#pragma unroll
        for (int r = 0; r < 4; r++) {
            int gr = row0 + m0 + quad * 4 + r;
            if (gr < M) {
                size_t o = (size_t)gr * DF + col;
                outL[o] = (_Float16)accL[nt][r];
                outR[o] = (_Float16)accR[nt][r];
            }
        }
    }
}

// ---------------------------------------------------------------------------
// CSR pass 2 body: one 512-thread block per fine bucket (391 blocks).
// Global bucket prefix via direct 512-wide ping-pong scan; local 128-node
// sort. LDS: 6144 + 3*128 + 2*512 ints = 30,208 B.
// ---------------------------------------------------------------------------
__device__ __forceinline__ void csr_body(
    int b, const int* __restrict__ g_count, const int* __restrict__ bucket_mem,
    int* __restrict__ row_ptr, unsigned short* __restrict__ csr_src, char* smem_)
{
    int* sh_edges = (int*)smem_;          // 6144 ints
    int* hist = sh_edges + 6144;          // 128
    int* excl = hist + 128;               // 128
    int* cnt2 = excl + 128;               // 128
    int* sA   = cnt2 + 128;               // 512
    int* sB   = sA + 512;                 // 512
    const int tid = threadIdx.x;          // 0..511

    // inclusive prefix scan over 391 bucket sizes (padded to 512)
    sA[tid] = (tid < NB2) ? g_count[tid] : 0;
    __syncthreads();
    int* in = sA; int* outp = sB;
    for (int d = 1; d < 512; d <<= 1) {
        outp[tid] = in[tid] + ((tid >= d) ? in[tid - d] : 0);
        __syncthreads();
        int* tmp = in; in = outp; outp = tmp;
    }
    const int base_csr = (b > 0) ? in[b - 1] : 0;

    int m = g_count[b]; if (m > CAP2) m = CAP2;
    if (tid < 128) { hist[tid] = 0; cnt2[tid] = 0; }
    __syncthreads();
    const int* bm = bucket_mem + (size_t)b * CAP2;
    for (int i = tid; i < m; i += 512) {
        int p = bm[i];
        sh_edges[i] = p;
        atomicAdd(&hist[(p >> 16) & 127], 1);
    }
    __syncthreads();
    if (tid < 128) sA[tid] = hist[tid];
    __syncthreads();
    for (int d = 1; d < 128; d <<= 1) {
        int x = 0;
        if (tid < 128 && tid >= d) x = sA[tid - d];
        __syncthreads();
        if (tid < 128) sA[tid] += x;
        __syncthreads();
    }
    if (tid < 128) {
        excl[tid] = sA[tid] - hist[tid];
        int node = (b << 7) + tid;
        if (node < N_NODES) row_ptr[node] = base_csr + excl[tid];
    }
    if (b == 0 && tid == 0) row_ptr[N_NODES] = ET;
    __syncthreads();
    for (int i = tid; i < m; i += 512) {
        int p = sh_edges[i];
        int dl = (p >> 16) & 127;
        int r = atomicAdd(&cnt2[dl], 1);
        csr_src[base_csr + excl[dl] + r] = (unsigned short)(p & 0xFFFF);
    }
}

// Dispatch 2: layer-1 GEMM overlapped with CSR pass 2 (csr depends only on
// the bin pass from dispatch 1, not on the GEMM). 512-thread blocks.
__global__ __launch_bounds__(512) void gemm_csr(
    const float* __restrict__ X,
    const _Float16* __restrict__ WhL, const _Float16* __restrict__ WhR,
    _Float16* __restrict__ outL, _Float16* __restrict__ outR,
    const int* __restrict__ g_count, const int* __restrict__ bucket_mem,
    int* __restrict__ row_ptr, unsigned short* __restrict__ csr_src)
{
    __shared__ char smem[30720];
    if (blockIdx.x < GEMM_BLOCKS2)
        gemm_body<float>(blockIdx.x, X, WhL, WhR, outL, outR, N_NODES, smem);
    else
        csr_body(blockIdx.x - GEMM_BLOCKS2, g_count, bucket_mem,
                 row_ptr, csr_src, smem);
}

// Layer-2 GEMM: fp16 input (layer-1 activations; zero-cvt staging).
__global__ __launch_bounds__(512) void gemm_f16(
    const _Float16* __restrict__ X,
    const _Float16* __restrict__ WhL, const _Float16* __restrict__ WhR,
    _Float16* __restrict__ outL, _Float16* __restrict__ outR)
{
    __shared__ char smem[30720];
    gemm_body<_Float16>(blockIdx.x, X, WhL, WhR, outL, outR, N_NODES, smem);
}

// ---------------------------------------------------------------------------
// Full-width fused scores + softmax + aggregate (R17 structure, full-range
// single dispatch -- R22's half-split cost ~14 us in launch/tail overhead).
// exp2/LOG2E pre-scale retained (R22-validated, absmax unchanged): att is
// pre-multiplied by log2(e) so the per-edge exp is a bare v_exp (exp2f).
// ---------------------------------------------------------------------------
template<typename TOut>
__global__ __launch_bounds__(256) void fused_agg(
    const _Float16* __restrict__ XL, const _Float16* __restrict__ XR,
    const int* __restrict__ row_ptr, const unsigned short* __restrict__ csr_src,
    const float* __restrict__ att, const float* __restrict__ bias,
    TOut* __restrict__ out)
{
    const int t = threadIdx.x;
    const int wave = t >> 6, l = t & 63;
    const int g = l >> 4, gl = l & 15;       // edge group 0..3, lane in group
    const int n = blockIdx.x * 4 + wave;
    if (n >= N_NODES) return;
    const int beg = row_ptr[n], end = row_ptr[n + 1];
    const int deg = end - beg;
    const int dlim = (deg < 128) ? deg : 128;

    // ---- coalesced CSR-index preload: lane l holds positions l and l+64,
    // packed low/high 16 bits (node ids < 50000 fit in 16 bits).
    const int liA = beg + l, liB = liA + 64;
    unsigned sa = (liA < end) ? (unsigned)csr_src[liA] : 0u;
    unsigned sb = (liB < end) ? (unsigned)csr_src[liB] : 0u;
    const unsigned s32 = sa | (sb << 16);

    const int c0 = gl * 8;                   // channels c0..c0+7
    half8 xrh = *(const half8*)(XR + (size_t)n * DF + c0);
    const float LOG2E = 1.44269504088896340736f;
    float4 at0 = *(const float4*)(att + c0);
    float4 at1 = *(const float4*)(att + c0 + 4);
    half2v a01 = { (_Float16)(at0.x * LOG2E), (_Float16)(at0.y * LOG2E) };
    half2v a23 = { (_Float16)(at0.z * LOG2E), (_Float16)(at0.w * LOG2E) };
    half2v a45 = { (_Float16)(at1.x * LOG2E), (_Float16)(at1.y * LOG2E) };
    half2v a67 = { (_Float16)(at1.z * LOG2E), (_Float16)(at1.w * LOG2E) };
    const half8 slp = { (_Float16)SLOPE, (_Float16)SLOPE, (_Float16)SLOPE, (_Float16)SLOPE,
                        (_Float16)SLOPE, (_Float16)SLOPE, (_Float16)SLOPE, (_Float16)SLOPE };

    float a0 = 0.f, a1 = 0.f, a2 = 0.f, a3 = 0.f;
    float a4 = 0.f, a5 = 0.f, a6 = 0.f, a7 = 0.f, den = 0.f;

    // source index for edge position POS (0..127): one ds_bpermute + select.
#define SRC(POS)                                                               \
    ({ int _p = (POS);                                                         \
       unsigned _v = (unsigned)__shfl((int)s32, _p & 63);                      \
       (int)(((_p & 64) ? (_v >> 16) : _v) & 0xFFFFu); })
#define LDROW(S) (*(const half8*)(XL + ((size_t)(unsigned)(S) << 7) + c0))

    // NOTE: _ok MUST be evaluated before any macro-local declarations so the
    // EOK expression sees the enclosing scope's loop variable (macro hygiene).
    // Score: FOUR fdot2 chains (m01,m23,m45,m67) -- all 8 channels.
#define EDGE_STEP(HV, EOK)                                                     \
    {                                                                          \
        const bool _ok = (EOK);                                                \
        half8 _msg = HV + xrh;                                                 \
        half8 _lk  = __builtin_elementwise_max(_msg, _msg * slp);              \
        half2v _m01 = { _lk[0], _lk[1] };                                      \
        half2v _m23 = { _lk[2], _lk[3] };                                      \
        half2v _m45 = { _lk[4], _lk[5] };                                      \
        half2v _m67 = { _lk[6], _lk[7] };                                      \
        float _sc = __builtin_amdgcn_fdot2(_m01, a01, 0.f, false);             \
        _sc = __builtin_amdgcn_fdot2(_m23, a23, _sc, false);                   \
        _sc = __builtin_amdgcn_fdot2(_m45, a45, _sc, false);                   \
        _sc = __builtin_amdgcn_fdot2(_m67, a67, _sc, false);                   \
        _sc += __shfl_xor(_sc, 1);                                             \
        _sc += __shfl_xor(_sc, 2);                                             \
        float _e = _ok ? exp2f(_sc) : 0.f;                                     \
        uint4 _hw; __builtin_memcpy(&_hw, &(HV), 16);                          \
        asm("v_fma_mix_f32 %0, %1, %2, %0 op_sel:[0,0,0] op_sel_hi:[1,0,0]"    \
            : "+v"(a0) : "v"(_hw.x), "v"(_e));                                 \
        asm("v_fma_mix_f32 %0, %1, %2, %0 op_sel:[1,0,0] op_sel_hi:[1,0,0]"    \
            : "+v"(a1) : "v"(_hw.x), "v"(_e));                                 \
        asm("v_fma_mix_f32 %0, %1, %2, %0 op_sel:[0,0,0] op_sel_hi:[1,0,0]"    \
            : "+v"(a2) : "v"(_hw.y), "v"(_e));                                 \
        asm("v_fma_mix_f32 %0, %1, %2, %0 op_sel:[1,0,0] op_sel_hi:[1,0,0]"    \
            : "+v"(a3) : "v"(_hw.y), "v"(_e));                                 \
        asm("v_fma_mix_f32 %0, %1, %2, %0 op_sel:[0,0,0] op_sel_hi:[1,0,0]"    \
            : "+v"(a4) : "v"(_hw.z), "v"(_e));                                 \
        asm("v_fma_mix_f32 %0, %1, %2, %0 op_sel:[1,0,0] op_sel_hi:[1,0,0]"    \
            : "+v"(a5) : "v"(_hw.z), "v"(_e));                                 \
        asm("v_fma_mix_f32 %0, %1, %2, %0 op_sel:[0,0,0] op_sel_hi:[1,0,0]"    \
            : "+v"(a6) : "v"(_hw.w), "v"(_e));                                 \
        asm("v_fma_mix_f32 %0, %1, %2, %0 op_sel:[1,0,0] op_sel_hi:[1,0,0]"    \
            : "+v"(a7) : "v"(_hw.w), "v"(_e));                                 \
        den += _e;                                                             \
    }

    // ---- ping-pong pipeline: 4 bufs = 16 positions in flight, phases of
    // 8 positions, zero register rotation.
    half8 X0 = LDROW(SRC(g));
    half8 X1 = LDROW(SRC(4 + g));
    half8 Y0 = LDROW(SRC(8 + g));
    half8 Y1 = LDROW(SRC(12 + g));

    int p = 0;
    for (;;) {
        // phase A: consume X0,X1 (pos p, p+4); refill with p+16, p+20
        EDGE_STEP(X0, (p + g < dlim))
        EDGE_STEP(X1, (p + 4 + g < dlim))
        X0 = LDROW(SRC(p + 16 + g));
        X1 = LDROW(SRC(p + 20 + g));
        p += 8;
        if (p >= dlim) break;
        // phase B: roles swapped
        EDGE_STEP(Y0, (p + g < dlim))
        EDGE_STEP(Y1, (p + 4 + g < dlim))
        Y0 = LDROW(SRC(p + 16 + g));
        Y1 = LDROW(SRC(p + 20 + g));
        p += 8;
        if (p >= dlim) break;
    }

    // ---- tail for deg > 128 (direct loads; never taken for this input) ----
    for (int q = 128; q < deg; q += 4) {
        int ei_ = beg + q + g;
        int s = (ei_ < end) ? (int)csr_src[ei_] : 0;
        half8 hvt = LDROW(s);
        EDGE_STEP(hvt, (q + g < deg))
    }
#undef EDGE_STEP
#undef SRC
#undef LDROW

#define CMB(x) x += __shfl_xor(x, 16); x += __shfl_xor(x, 32);
    CMB(a0) CMB(a1) CMB(a2) CMB(a3) CMB(a4) CMB(a5) CMB(a6) CMB(a7) CMB(den)
#undef CMB

    if (g == 0) {
        float inv = 1.f / (den + 1e-16f);     // den is this lane's head's total
        float4 b0 = *(const float4*)(bias + c0);
        float4 b1 = *(const float4*)(bias + c0 + 4);
        float o[8];
        o[0] = fmaxf(a0 * inv + b0.x, 0.f);
        o[1] = fmaxf(a1 * inv + b0.y, 0.f);
        o[2] = fmaxf(a2 * inv + b0.z, 0.f);
        o[3] = fmaxf(a3 * inv + b0.w, 0.f);
        o[4] = fmaxf(a4 * inv + b1.x, 0.f);
        o[5] = fmaxf(a5 * inv + b1.y, 0.f);
        o[6] = fmaxf(a6 * inv + b1.z, 0.f);
        o[7] = fmaxf(a7 * inv + b1.w, 0.f);
        TOut* op = out + (size_t)n * DF + c0;
        if constexpr (sizeof(TOut) == 2) {
            half8 hv;
#pragma unroll
            for (int i = 0; i < 8; i++) hv[i] = (_Float16)o[i];
            *(half8*)op = hv;
        } else {
            *(float4*)(op)     = make_float4(o[0], o[1], o[2], o[3]);
            *(float4*)(op + 4) = make_float4(o[4], o[5], o[6], o[7]);
        }
    }
}

// ---------------------------------------------------------------------------
extern "C" void kernel_launch(void* const* d_in, const int* in_sizes, int n_in,
                              void* d_out, int out_size, void* d_ws, size_t ws_size,
                              hipStream_t stream)
{
    (void)in_sizes; (void)n_in; (void)out_size; (void)ws_size;

    const float* x    = (const float*)d_in[0];
    const int*   ei   = (const int*)d_in[1];
    const float* W1l  = (const float*)d_in[2];
    const float* W1r  = (const float*)d_in[3];
    const float* att1 = (const float*)d_in[4];
    const float* b1   = (const float*)d_in[5];
    const float* W2l  = (const float*)d_in[6];
    const float* W2r  = (const float*)d_in[7];
    const float* att2 = (const float*)d_in[8];
    const float* b2   = (const float*)d_in[9];
    float* out = (float*)d_out;

    char* ws = (char*)d_ws;
    size_t off = 0;
    const size_t NF = (size_t)N_NODES * DF * sizeof(float);        // 25.6 MB
    _Float16* A = (_Float16*)(ws + off); off += NF / 2;            // xl fp16 [N][128]
    _Float16* B = (_Float16*)(ws + off); off += NF / 2;            // xr fp16 [N][128]
    _Float16* C = (_Float16*)(ws + off); off += NF / 2;            // layer-1 out fp16
    int* bucket_mem  = (int*)(ws + off); off += (size_t)NB2 * CAP2 * sizeof(int);
    int* g_count     = (int*)(ws + off); off += 512 * sizeof(int);
    int* row_ptr     = (int*)(ws + off); off += (size_t)(N_NODES + 1) * sizeof(int);
    unsigned short* csr_src = (unsigned short*)(ws + off);
    off += ((size_t)ET * sizeof(unsigned short) + 255) & ~(size_t)255;
    _Float16* Wh = (_Float16*)(ws + off); off += 4 * 16384 * sizeof(_Float16);

    // zero bucket counters (graph-capture-safe stream memset)
    hipMemsetAsync(g_count, 0, 512 * sizeof(int), stream);

    // ---- dispatch 1: W cast overlapped with CSR bin pass ----
    prep_bin<<<WCONV_BLOCKS + BIN_BLOCKS, 256, 0, stream>>>(
        W1l, W1r, W2l, W2r, Wh, ei, g_count, bucket_mem);

    // ---- dispatch 2: layer-1 GEMM overlapped with CSR pass 2 ----
    gemm_csr<<<GEMM_BLOCKS2 + NB2, 512, 0, stream>>>(
        x, Wh, Wh + 16384, A, B, g_count, bucket_mem, row_ptr, csr_src);

    fused_agg<_Float16><<<(N_NODES + 3) / 4, 256, 0, stream>>>(
        A, B, row_ptr, csr_src, att1, b1, C);

    // ---- layer 2 ----
    gemm_f16<<<GEMM_BLOCKS2, 512, 0, stream>>>(
        C, Wh + 2 * 16384, Wh + 3 * 16384, A, B);
    fused_agg<float><<<(N_NODES + 3) / 4, 256, 0, stream>>>(
        A, B, row_ptr, csr_src, att2, b2, out);
}